// Round 1
// 1004.925 us; speedup vs baseline: 1.6632x; 1.6632x over previous
//
#include <hip/hip_runtime.h>

typedef unsigned short u16;
typedef unsigned int u32;
typedef __attribute__((ext_vector_type(8))) short short8;
typedef __attribute__((ext_vector_type(4))) float floatx4;

#define EDIM 1024
#define H3   3072
#define HD   64

__device__ __forceinline__ float bf2f(u16 u) {
    union { u32 i; float f; } x; x.i = ((u32)u) << 16; return x.f;
}
__device__ __forceinline__ u16 f2bf(float f) {
    u32 u = __float_as_uint(f);
    u32 r = u + 0x7fffu + ((u >> 16) & 1u);
    return (u16)(r >> 16);
}

// ---------------------------------------------------------------------------
// Detect input dtype (bf16 vs fp32) from bit patterns. flag=1 -> bf16.
// ---------------------------------------------------------------------------
__global__ void detect_dtype(const u16* __restrict__ t, int* __restrict__ flag)
{
    __shared__ int cnt;
    if (threadIdx.x == 0) cnt = 0;
    __syncthreads();
    u16 u = t[threadIdx.x * 2];
    int e = (u >> 7) & 0xFF;
    int ok = (u == 0) || (e >= 108 && e <= 136);
    atomicAdd(&cnt, ok);
    __syncthreads();
    if (threadIdx.x == 0) flag[0] = (cnt >= 128) ? 1 : 0;
}

// ---------------------------------------------------------------------------
// Convert two arrays (fp32->bf16, or plain copy when input already bf16).
// Counts are in units of 8 elements. All array sizes here are /8 divisible.
// ---------------------------------------------------------------------------
__global__ __launch_bounds__(256) void to_bf16_2(
    const void* __restrict__ sa, u16* __restrict__ da, int na8,
    const void* __restrict__ sb, u16* __restrict__ db, int nb8,
    const int* __restrict__ flag)
{
    int idx = blockIdx.x * 256 + threadIdx.x;
    const void* s; u16* d; long off;
    if (idx < na8) {
        s = sa; d = da; off = (long)idx * 8;
    } else {
        idx -= na8;
        if (idx >= nb8) return;
        s = sb; d = db; off = (long)idx * 8;
    }
    if (flag[0]) {
        *(uint4*)(d + off) = *(const uint4*)((const u16*)s + off);
    } else {
        const float* f = (const float*)s + off;
        float4 f0 = *(const float4*)f;
        float4 f1 = *(const float4*)(f + 4);
        uint4 p;
        p.x = (u32)f2bf(f0.x) | ((u32)f2bf(f0.y) << 16);
        p.y = (u32)f2bf(f0.z) | ((u32)f2bf(f0.w) << 16);
        p.z = (u32)f2bf(f1.x) | ((u32)f2bf(f1.y) << 16);
        p.w = (u32)f2bf(f1.z) | ((u32)f2bf(f1.w) << 16);
        *(uint4*)(d + off) = p;
    }
}

// ---------------------------------------------------------------------------
// C[M,N] = A[M,K] @ W[N,K]^T + bias[N], all bf16. 1D grid with supertile
// swizzle (groups of 8 m-tiles). global_load_lds width-16 staging (m97
// structure). fp32 fallback removed: everything is pre-converted to bf16.
// ---------------------------------------------------------------------------
__global__ __launch_bounds__(256) void gemm_bt_bias(
    const u16* __restrict__ A, const u16* __restrict__ W,
    const u16* __restrict__ bias, u16* __restrict__ C,
    int M, int N, int K, int w_row0, int b_off)
{
    __shared__ u16 sA[128 * 64];
    __shared__ u16 sB[128 * 64];
    const int tid  = threadIdx.x;
    const int wave = tid >> 6, lane = tid & 63;

    // ---- supertile swizzle ----
    const int MT = (M + 127) >> 7, NT = N >> 7;
    const int tpg = NT * 8;
    const int grp = blockIdx.x / tpg;
    const int rem = blockIdx.x - grp * tpg;
    int gsz = MT - grp * 8; if (gsz > 8) gsz = 8;
    const int mt = grp * 8 + rem % gsz;
    const int nt = rem / gsz;
    const int m0 = mt * 128, n0 = nt * 128;

    const int wm = (wave & 1) * 64, wn = (wave >> 1) * 64;
    const int r16 = lane & 15, q8 = (lane >> 4) * 8;
    const int lrow = lane >> 3, lcol = (lane & 7) * 8;

    floatx4 acc[4][4];
#pragma unroll
    for (int i = 0; i < 4; ++i)
#pragma unroll
        for (int j = 0; j < 4; ++j)
            acc[i][j] = (floatx4){0.f, 0.f, 0.f, 0.f};

    const u16* Wb = W + (size_t)w_row0 * K;
    for (int k0 = 0; k0 < K; k0 += 64) {
#pragma unroll
        for (int t = 0; t < 4; ++t) {
            int rr = wave * 32 + t * 8;
            int ga = m0 + rr + lrow; if (ga > M - 1) ga = M - 1;
            __builtin_amdgcn_global_load_lds(
                (const __attribute__((address_space(1))) void*)(A + (size_t)ga * K + k0 + lcol),
                (__attribute__((address_space(3))) void*)&sA[rr * 64], 16, 0, 0);
            int gb = n0 + rr + lrow; if (gb > N - 1) gb = N - 1;
            __builtin_amdgcn_global_load_lds(
                (const __attribute__((address_space(1))) void*)(Wb + (size_t)gb * K + k0 + lcol),
                (__attribute__((address_space(3))) void*)&sB[rr * 64], 16, 0, 0);
        }
        __syncthreads();
#pragma unroll
        for (int kk = 0; kk < 64; kk += 32) {
            short8 af[4], bg[4];
#pragma unroll
            for (int i = 0; i < 4; ++i)
                af[i] = *(const short8*)&sA[(wm + 16 * i + r16) * 64 + kk + q8];
#pragma unroll
            for (int j = 0; j < 4; ++j)
                bg[j] = *(const short8*)&sB[(wn + 16 * j + r16) * 64 + kk + q8];
#pragma unroll
            for (int i = 0; i < 4; ++i)
#pragma unroll
                for (int j = 0; j < 4; ++j)
                    acc[i][j] = __builtin_amdgcn_mfma_f32_16x16x32_bf16(
                        af[i], bg[j], acc[i][j], 0, 0, 0);
        }
        __syncthreads();
    }

#pragma unroll
    for (int j = 0; j < 4; ++j) {
        int col = n0 + wn + 16 * j + r16;
        float bv = bf2f(bias[b_off + col]);
#pragma unroll
        for (int i = 0; i < 4; ++i) {
            int rowb = m0 + wm + 16 * i + (lane >> 4) * 4;
#pragma unroll
            for (int r = 0; r < 4; ++r) {
                int row = rowb + r;
                if (row < M)
                    C[(size_t)row * N + col] = f2bf(acc[i][j][r] + bv);
            }
        }
    }
}

// ---------------------------------------------------------------------------
// MFMA flash attention (unchanged — passing).
// ---------------------------------------------------------------------------
__global__ __launch_bounds__(256) void attn_flash(
    const u16* __restrict__ qkv, u16* __restrict__ out, int L, int causal)
{
    __shared__ u16 sK[64 * 64];
    __shared__ u16 sVt[64 * 64];
    __shared__ u16 sP[4 * 16 * 64];
    const int tid = threadIdx.x;
    const int wave = tid >> 6, lane = tid & 63;
    const int h = blockIdx.y, g = blockIdx.z, qt = blockIdx.x;
    const size_t grow0 = (size_t)g * L;
    const int qw0 = qt * 64 + wave * 16;
    const int r16 = lane & 15, q8 = (lane >> 4) * 8;

    short8 qf0, qf1;
    {
        const u16* qp = qkv + (grow0 + qw0 + r16) * (size_t)H3 + h * HD + q8;
        qf0 = *(const short8*)qp;
        qf1 = *(const short8*)(qp + 32);
    }

    floatx4 o_acc[4];
#pragma unroll
    for (int dg = 0; dg < 4; ++dg) o_acc[dg] = (floatx4){0.f, 0.f, 0.f, 0.f};
    float m_r[4], l_r[4];
#pragma unroll
    for (int r = 0; r < 4; ++r) { m_r[r] = -3.0e38f; l_r[r] = 0.f; }

    u16* sPw = sP + wave * 1024;
    const int nch = causal ? (qt + 1) : (L >> 6);

    for (int c = 0; c < nch; ++c) {
        const int k0 = c * 64;
        __syncthreads();
#pragma unroll
        for (int t = 0; t < 2; ++t) {
            int idx = t * 256 + tid;
            int r = idx >> 3, c8 = (idx & 7) * 8;
            const u16* kp = qkv + (grow0 + k0 + r) * (size_t)H3 + EDIM + h * HD + c8;
            *(uint4*)&sK[r * 64 + c8] = *(const uint4*)kp;
            uint4 vw = *(const uint4*)(kp + EDIM);
            u32 vu[4] = {vw.x, vw.y, vw.z, vw.w};
#pragma unroll
            for (int i = 0; i < 4; ++i) {
                sVt[(c8 + 2 * i) * 64 + r]     = (u16)(vu[i] & 0xffffu);
                sVt[(c8 + 2 * i + 1) * 64 + r] = (u16)(vu[i] >> 16);
            }
        }
        __syncthreads();

        float sc[4][4];
#pragma unroll
        for (int kg = 0; kg < 4; ++kg) {
            const u16* kb = &sK[(kg * 16 + r16) * 64];
            short8 kf0 = *(const short8*)(kb + q8);
            short8 kf1 = *(const short8*)(kb + 32 + q8);
            floatx4 a = (floatx4){0.f, 0.f, 0.f, 0.f};
            a = __builtin_amdgcn_mfma_f32_16x16x32_bf16(qf0, kf0, a, 0, 0, 0);
            a = __builtin_amdgcn_mfma_f32_16x16x32_bf16(qf1, kf1, a, 0, 0, 0);
#pragma unroll
            for (int r = 0; r < 4; ++r) sc[kg][r] = a[r] * 0.125f;
        }
        const bool domask = causal && (k0 + 63 > qw0);
        if (domask) {
#pragma unroll
            for (int kg = 0; kg < 4; ++kg)
#pragma unroll
                for (int r = 0; r < 4; ++r) {
                    int key = k0 + kg * 16 + r16;
                    int qg  = qw0 + (lane >> 4) * 4 + r;
                    if (key > qg) sc[kg][r] = -3.0e38f;
                }
        }
        float rmax[4];
#pragma unroll
        for (int r = 0; r < 4; ++r)
            rmax[r] = fmaxf(fmaxf(sc[0][r], sc[1][r]), fmaxf(sc[2][r], sc[3][r]));
#pragma unroll
        for (int m = 1; m <= 8; m <<= 1)
#pragma unroll
            for (int r = 0; r < 4; ++r)
                rmax[r] = fmaxf(rmax[r], __shfl_xor(rmax[r], m));
        float alpha[4], rsum[4];
#pragma unroll
        for (int r = 0; r < 4; ++r) {
            float mn = fmaxf(m_r[r], rmax[r]);
            alpha[r] = __expf(m_r[r] - mn);
            m_r[r] = mn; rsum[r] = 0.f;
        }
#pragma unroll
        for (int kg = 0; kg < 4; ++kg)
#pragma unroll
            for (int r = 0; r < 4; ++r) {
                float p = __expf(sc[kg][r] - m_r[r]);
                rsum[r] += p;
                sPw[((lane >> 4) * 4 + r) * 64 + kg * 16 + r16] = f2bf(p);
            }
#pragma unroll
        for (int m = 1; m <= 8; m <<= 1)
#pragma unroll
            for (int r = 0; r < 4; ++r)
                rsum[r] += __shfl_xor(rsum[r], m);
#pragma unroll
        for (int r = 0; r < 4; ++r) l_r[r] = l_r[r] * alpha[r] + rsum[r];
#pragma unroll
        for (int dg = 0; dg < 4; ++dg)
#pragma unroll
            for (int r = 0; r < 4; ++r) o_acc[dg][r] *= alpha[r];

        __asm__ volatile("" ::: "memory");

#pragma unroll
        for (int kc = 0; kc < 2; ++kc) {
            short8 pf = *(const short8*)&sPw[r16 * 64 + kc * 32 + q8];
#pragma unroll
            for (int dg = 0; dg < 4; ++dg) {
                short8 vf = *(const short8*)&sVt[(dg * 16 + r16) * 64 + kc * 32 + q8];
                o_acc[dg] = __builtin_amdgcn_mfma_f32_16x16x32_bf16(pf, vf, o_acc[dg], 0, 0, 0);
            }
        }
    }

    float inv[4];
#pragma unroll
    for (int r = 0; r < 4; ++r) inv[r] = 1.f / l_r[r];
#pragma unroll
    for (int dg = 0; dg < 4; ++dg)
#pragma unroll
        for (int r = 0; r < 4; ++r) {
            int q = qw0 + (lane >> 4) * 4 + r;
            out[(grow0 + q) * (size_t)EDIM + h * HD + dg * 16 + r16] =
                f2bf(o_acc[dg][r] * inv[r]);
        }
}

// ---------------------------------------------------------------------------
// Single-query cross attention. One wave per (head, group).
// ---------------------------------------------------------------------------
__global__ __launch_bounds__(64) void attn_cross(
    const u16* __restrict__ kv, const u16* __restrict__ qv,
    u16* __restrict__ out, int mode)
{
    const int h = blockIdx.x, gi = blockIdx.y, lane = threadIdx.x;
    int Lk, kvStride, kOff, vOff, qRow;
    size_t kvRow0;
    if (mode == 0) {
        Lk = 256; kvStride = H3; kOff = EDIM; vOff = 2 * EDIM;
        kvRow0 = (size_t)gi * 256;
        int s = gi >> 2, b = gi & 3;
        qRow = b * 16 + s;
    } else {
        Lk = 1040; kvStride = 2 * EDIM; kOff = 0; vOff = EDIM;
        kvRow0 = (size_t)gi * 1040;
        qRow = gi;
    }
    __shared__ float sq[64];
    __shared__ float sp[1040];
    sq[lane] = bf2f(qv[(size_t)qRow * EDIM + h * HD + lane]);
    __syncthreads();

    const int nt = (Lk + 63) >> 6;
    float mloc = -3.0e38f;
    for (int t = 0; t < nt; ++t) {
        int j = t * 64 + lane;
        if (j < Lk) {
            const uint4* kp = (const uint4*)(kv + (kvRow0 + j) * (size_t)kvStride + kOff + h * HD);
            float a0 = 0, a1 = 0;
#pragma unroll
            for (int tt = 0; tt < 8; ++tt) {
                uint4 w = kp[tt];
                u32 u[4] = {w.x, w.y, w.z, w.w};
#pragma unroll
                for (int i = 0; i < 4; ++i) {
                    a0 += sq[tt * 8 + i * 2]     * bf2f((u16)(u[i] & 0xffffu));
                    a1 += sq[tt * 8 + i * 2 + 1] * bf2f((u16)(u[i] >> 16));
                }
            }
            float s_ = (a0 + a1) * 0.125f;
            sp[j] = s_;
            mloc = fmaxf(mloc, s_);
        }
    }
#pragma unroll
    for (int off = 32; off; off >>= 1) mloc = fmaxf(mloc, __shfl_xor(mloc, off));
    float lsum = 0.f;
    for (int t = 0; t < nt; ++t) {
        int j = t * 64 + lane;
        if (j < Lk) { float p = __expf(sp[j] - mloc); sp[j] = p; lsum += p; }
    }
#pragma unroll
    for (int off = 32; off; off >>= 1) lsum += __shfl_xor(lsum, off);
    __syncthreads();

    float o = 0.f;
    for (int j = 0; j < Lk; ++j)
        o += sp[j] * bf2f(kv[(kvRow0 + j) * (size_t)kvStride + vOff + h * HD + lane]);
    out[(size_t)qRow * EDIM + h * HD + lane] = f2bf(o / lsum);
}

// ---------------------------------------------------------------------------
__global__ __launch_bounds__(256) void build_ctx(
    const u16* __restrict__ to, const u16* __restrict__ co, u16* __restrict__ ctx)
{
    int idx = blockIdx.x * 256 + threadIdx.x;
    int row = idx >> 7, c8 = (idx & 127) << 3;
    int b = row / 1040, t = row - b * 1040;
    const u16* src = (t < 1024)
        ? (to + ((size_t)(b * 1024 + t) * EDIM + c8))
        : (co + ((size_t)(b * 16 + (t - 1024)) * EDIM + c8));
    *(uint4*)(ctx + (size_t)row * EDIM + c8) = *(const uint4*)src;
}

// ---------------------------------------------------------------------------
__global__ __launch_bounds__(256) void emit_out(
    const u16* __restrict__ src, void* __restrict__ dst, int n8,
    const int* __restrict__ flag)
{
    int idx = blockIdx.x * 256 + threadIdx.x;
    if (idx >= n8) return;
    const u16* s = src + (size_t)idx * 8;
    if (flag[0]) {
        *(uint4*)((u16*)dst + (size_t)idx * 8) = *(const uint4*)s;
    } else {
        float4 f0, f1;
        f0.x = bf2f(s[0]); f0.y = bf2f(s[1]); f0.z = bf2f(s[2]); f0.w = bf2f(s[3]);
        f1.x = bf2f(s[4]); f1.y = bf2f(s[5]); f1.z = bf2f(s[6]); f1.w = bf2f(s[7]);
        float4* dp = (float4*)dst + (size_t)idx * 2;
        dp[0] = f0; dp[1] = f1;
    }
}

// ---------------------------------------------------------------------------
// Workspace live-range plan (u16 offsets from ws base; peak unchanged 168 MB):
//   flag       [0,64)
//   qkv_text   [64, 12582976)          : QKV text; later WO1/WO2 scratch, then
//                                        ctx [+0,4259840) + WI [+4259840) + WIO [+7408640)
//   qkv_patch  [12582976, 62914624)    : WT scratch -> QKV patch -> kv_int/q_int/attn_int/out_ws
//   attn_text  [62914624, 67108928)    : text_bf -> WP scratch -> attn text out
//   attn_patch [67108928, 83886144)    : patch_bf -> attn patch out
//   cls_q      [83886144, 83951680)    : cls_q -> int_bf scratch
//   attn_cls   [83951680, 84017216)    : cls_bf -> attn cls out
// ---------------------------------------------------------------------------
extern "C" void kernel_launch(void* const* d_in, const int* in_sizes, int n_in,
                              void* d_out, int out_size, void* d_ws, size_t ws_size,
                              hipStream_t stream)
{
    const void* text  = d_in[0];
    const void* patch = d_in[1];
    const void* cls   = d_in[2];
    const void* intok = d_in[3];
    const void* t_win  = d_in[4];  const void* t_bin  = d_in[5];
    const void* t_wout = d_in[6];  const void* t_bout = d_in[7];
    const void* p_win  = d_in[8];  const void* p_bin  = d_in[9];
    const void* p_wout = d_in[10]; const void* p_bout = d_in[11];
    const void* i_win  = d_in[12]; const void* i_bin  = d_in[13];
    const void* i_wout = d_in[14]; const void* i_bout = d_in[15];

    u16* ws = (u16*)d_ws;
    int* flag       = (int*)d_ws;
    u16* qkv_text   = ws + 64;
    u16* qkv_patch  = ws + 12582976;
    u16* attn_text  = ws + 62914624;
    u16* attn_patch = ws + 67108928;
    u16* cls_q      = ws + 83886144;
    u16* attn_cls   = ws + 83951680;

    // converted activations (in regions dead until the attn kernels write them)
    u16* text_bf  = attn_text;            // 4194304, dead after text QKV gemm
    u16* patch_bf = attn_patch;           // 16777216, dead after patch QKV gemm
    u16* cls_bf   = attn_cls;             // 65536, dead after cls_q gemm
    u16* int_bf   = cls_q;                // 4096, converted late (cls_q dead)
    // converted weights (scratch rotates through dead regions)
    u16* WT   = qkv_patch;                // t_win(3145728)+t_bin; dead after text QKV
    u16* WTb  = WT + 3145728;
    u16* WP   = attn_text;                // p_win+p_bin; after text QKV (text_bf dead)
    u16* WPb  = WP + 3145728;
    u16* WO1  = qkv_text;                 // t_wout+t_bout; after attn text (qkv_text dead)
    u16* WO1b = WO1 + 1048576;
    u16* WO2  = qkv_text + 1049600;       // p_wout+p_bout
    u16* WO2b = WO2 + 1048576;
    u16* WI   = qkv_text + 4259840;       // i_win+i_bin (survives ctx build)
    u16* WIb  = WI + 3145728;
    u16* WIO  = qkv_text + 7408640;       // i_wout+i_bout (survives to end)
    u16* WIOb = WIO + 1048576;
    // INT-path reuse of qkv_patch region
    u16* ctx      = qkv_text;
    u16* kv_int   = qkv_patch;
    u16* q_int    = qkv_patch + 8519680;
    u16* attn_int = qkv_patch + 8523776;
    u16* out_ws   = qkv_patch + 8527872;
    u16* to_ws = out_ws;
    u16* po_ws = out_ws + 4194304;
    u16* co_ws = out_ws + 20971520;
    u16* io_ws = out_ws + 21037056;

    dim3 blk(256);
    detect_dtype<<<1, blk, 0, stream>>>((const u16*)text, flag);

    // --- stage 0: convert activations + text QKV weights to bf16 ---
    to_bf16_2<<<dim3(10240), blk, 0, stream>>>(text, text_bf, 524288,
                                               patch, patch_bf, 2097152, flag);
    to_bf16_2<<<dim3(32), blk, 0, stream>>>(cls, cls_bf, 8192, cls, cls_bf, 0, flag);
    to_bf16_2<<<dim3(1538), blk, 0, stream>>>(t_win, WT, 393216, t_bin, WTb, 384, flag);

    // --- text QKV (fast bf16 path) ---
    gemm_bt_bias<<<dim3(32 * 24), blk, 0, stream>>>(text_bf, WT, WTb, qkv_text,
                                                    4096, 3072, 1024, 0, 0);
    // --- patch weights (into attn_text region, text_bf now dead) ---
    to_bf16_2<<<dim3(1538), blk, 0, stream>>>(p_win, WP, 393216, p_bin, WPb, 384, flag);
    gemm_bt_bias<<<dim3(128 * 24), blk, 0, stream>>>(patch_bf, WP, WPb, qkv_patch,
                                                     16384, 3072, 1024, 0, 0);
    gemm_bt_bias<<<dim3(1 * 8), blk, 0, stream>>>(cls_bf, WP, WPb, cls_q,
                                                  64, 1024, 1024, 0, 0);

    // --- attention (WP/patch_bf/cls_bf dead; outputs overwrite them) ---
    attn_flash<<<dim3(16, 16, 4), blk, 0, stream>>>(qkv_text, attn_text, 1024, 1);
    attn_flash<<<dim3(4, 16, 64), blk, 0, stream>>>(qkv_patch, attn_patch, 256, 0);
    attn_cross<<<dim3(16, 64), dim3(64), 0, stream>>>(qkv_patch, cls_q, attn_cls, 0);

    // --- output-proj + INT weights (qkv_text dead after attn text) ---
    to_bf16_2<<<dim3(513), blk, 0, stream>>>(t_wout, WO1, 131072, t_bout, WO1b, 128, flag);
    to_bf16_2<<<dim3(513), blk, 0, stream>>>(p_wout, WO2, 131072, p_bout, WO2b, 128, flag);
    to_bf16_2<<<dim3(1538), blk, 0, stream>>>(i_win, WI, 393216, i_bin, WIb, 384, flag);
    to_bf16_2<<<dim3(513), blk, 0, stream>>>(i_wout, WIO, 131072, i_bout, WIOb, 128, flag);

    // --- output projections (qkv_patch dead -> out_ws region free) ---
    gemm_bt_bias<<<dim3(32 * 8), blk, 0, stream>>>(attn_text, WO1, WO1b, to_ws,
                                                   4096, 1024, 1024, 0, 0);
    gemm_bt_bias<<<dim3(128 * 8), blk, 0, stream>>>(attn_patch, WO2, WO2b, po_ws,
                                                    16384, 1024, 1024, 0, 0);
    gemm_bt_bias<<<dim3(1 * 8), blk, 0, stream>>>(attn_cls, WO2, WO2b, co_ws,
                                                  64, 1024, 1024, 0, 0);

    // --- INT path ---
    build_ctx<<<dim3(2080), blk, 0, stream>>>(to_ws, co_ws, ctx);
    gemm_bt_bias<<<dim3(33 * 16), blk, 0, stream>>>(ctx, WI, WIb, kv_int,
                                                    4160, 2048, 1024, 1024, 1024);
    to_bf16_2<<<dim3(2), blk, 0, stream>>>(intok, int_bf, 512, intok, int_bf, 0, flag);
    gemm_bt_bias<<<dim3(1 * 8), blk, 0, stream>>>(int_bf, WI, WIb, q_int,
                                                  4, 1024, 1024, 0, 0);
    attn_cross<<<dim3(16, 4), dim3(64), 0, stream>>>(kv_int, q_int, attn_int, 1);
    gemm_bt_bias<<<dim3(1 * 8), blk, 0, stream>>>(attn_int, WIO, WIOb, io_ws,
                                                  4, 1024, 1024, 0, 0);

    // --- emit ---
    emit_out<<<dim3(10274), blk, 0, stream>>>(out_ws, d_out, 2630144, flag);
}

// Round 2
// 956.718 us; speedup vs baseline: 1.7470x; 1.0504x over previous
//
#include <hip/hip_runtime.h>

typedef unsigned short u16;
typedef unsigned int u32;
typedef __attribute__((ext_vector_type(8))) short short8;
typedef __attribute__((ext_vector_type(4))) float floatx4;

#define EDIM 1024
#define H3   3072
#define HD   64

__device__ __forceinline__ float bf2f(u16 u) {
    union { u32 i; float f; } x; x.i = ((u32)u) << 16; return x.f;
}
__device__ __forceinline__ u16 f2bf(float f) {
    u32 u = __float_as_uint(f);
    u32 r = u + 0x7fffu + ((u >> 16) & 1u);
    return (u16)(r >> 16);
}

// ---------------------------------------------------------------------------
// Detect input dtype (bf16 vs fp32) from bit patterns. flag=1 -> bf16.
// ---------------------------------------------------------------------------
__global__ void detect_dtype(const u16* __restrict__ t, int* __restrict__ flag)
{
    __shared__ int cnt;
    if (threadIdx.x == 0) cnt = 0;
    __syncthreads();
    u16 u = t[threadIdx.x * 2];
    int e = (u >> 7) & 0xFF;
    int ok = (u == 0) || (e >= 108 && e <= 136);
    atomicAdd(&cnt, ok);
    __syncthreads();
    if (threadIdx.x == 0) flag[0] = (cnt >= 128) ? 1 : 0;
}

// ---------------------------------------------------------------------------
// Convert two arrays (fp32->bf16, or plain copy when input already bf16).
// Counts are in units of 8 elements.
// ---------------------------------------------------------------------------
__global__ __launch_bounds__(256) void to_bf16_2(
    const void* __restrict__ sa, u16* __restrict__ da, int na8,
    const void* __restrict__ sb, u16* __restrict__ db, int nb8,
    const int* __restrict__ flag)
{
    int idx = blockIdx.x * 256 + threadIdx.x;
    const void* s; u16* d; long off;
    if (idx < na8) {
        s = sa; d = da; off = (long)idx * 8;
    } else {
        idx -= na8;
        if (idx >= nb8) return;
        s = sb; d = db; off = (long)idx * 8;
    }
    if (flag[0]) {
        *(uint4*)(d + off) = *(const uint4*)((const u16*)s + off);
    } else {
        const float* f = (const float*)s + off;
        float4 f0 = *(const float4*)f;
        float4 f1 = *(const float4*)(f + 4);
        uint4 p;
        p.x = (u32)f2bf(f0.x) | ((u32)f2bf(f0.y) << 16);
        p.y = (u32)f2bf(f0.z) | ((u32)f2bf(f0.w) << 16);
        p.z = (u32)f2bf(f1.x) | ((u32)f2bf(f1.y) << 16);
        p.w = (u32)f2bf(f1.z) | ((u32)f2bf(f1.w) << 16);
        *(uint4*)(d + off) = p;
    }
}

// ---------------------------------------------------------------------------
// 128^2-tile GEMM (m97 structure) — kept for small/narrow shapes.
// C[M,N] = A[M,K] @ W[N,K]^T + bias[N], all bf16.
// ---------------------------------------------------------------------------
__global__ __launch_bounds__(256) void gemm_bt_bias(
    const u16* __restrict__ A, const u16* __restrict__ W,
    const u16* __restrict__ bias, u16* __restrict__ C,
    int M, int N, int K, int w_row0, int b_off)
{
    __shared__ u16 sA[128 * 64];
    __shared__ u16 sB[128 * 64];
    const int tid  = threadIdx.x;
    const int wave = tid >> 6, lane = tid & 63;

    const int MT = (M + 127) >> 7, NT = N >> 7;
    const int tpg = NT * 8;
    const int grp = blockIdx.x / tpg;
    const int rem = blockIdx.x - grp * tpg;
    int gsz = MT - grp * 8; if (gsz > 8) gsz = 8;
    const int mt = grp * 8 + rem % gsz;
    const int nt = rem / gsz;
    const int m0 = mt * 128, n0 = nt * 128;

    const int wm = (wave & 1) * 64, wn = (wave >> 1) * 64;
    const int r16 = lane & 15, q8 = (lane >> 4) * 8;
    const int lrow = lane >> 3, lcol = (lane & 7) * 8;

    floatx4 acc[4][4];
#pragma unroll
    for (int i = 0; i < 4; ++i)
#pragma unroll
        for (int j = 0; j < 4; ++j)
            acc[i][j] = (floatx4){0.f, 0.f, 0.f, 0.f};

    const u16* Wb = W + (size_t)w_row0 * K;
    for (int k0 = 0; k0 < K; k0 += 64) {
#pragma unroll
        for (int t = 0; t < 4; ++t) {
            int rr = wave * 32 + t * 8;
            int ga = m0 + rr + lrow; if (ga > M - 1) ga = M - 1;
            __builtin_amdgcn_global_load_lds(
                (const __attribute__((address_space(1))) void*)(A + (size_t)ga * K + k0 + lcol),
                (__attribute__((address_space(3))) void*)&sA[rr * 64], 16, 0, 0);
            int gb = n0 + rr + lrow; if (gb > N - 1) gb = N - 1;
            __builtin_amdgcn_global_load_lds(
                (const __attribute__((address_space(1))) void*)(Wb + (size_t)gb * K + k0 + lcol),
                (__attribute__((address_space(3))) void*)&sB[rr * 64], 16, 0, 0);
        }
        __syncthreads();
#pragma unroll
        for (int kk = 0; kk < 64; kk += 32) {
            short8 af[4], bg[4];
#pragma unroll
            for (int i = 0; i < 4; ++i)
                af[i] = *(const short8*)&sA[(wm + 16 * i + r16) * 64 + kk + q8];
#pragma unroll
            for (int j = 0; j < 4; ++j)
                bg[j] = *(const short8*)&sB[(wn + 16 * j + r16) * 64 + kk + q8];
#pragma unroll
            for (int i = 0; i < 4; ++i)
#pragma unroll
                for (int j = 0; j < 4; ++j)
                    acc[i][j] = __builtin_amdgcn_mfma_f32_16x16x32_bf16(
                        af[i], bg[j], acc[i][j], 0, 0, 0);
        }
        __syncthreads();
    }

#pragma unroll
    for (int j = 0; j < 4; ++j) {
        int col = n0 + wn + 16 * j + r16;
        float bv = bf2f(bias[b_off + col]);
#pragma unroll
        for (int i = 0; i < 4; ++i) {
            int rowb = m0 + wm + 16 * i + (lane >> 4) * 4;
#pragma unroll
            for (int r = 0; r < 4; ++r) {
                int row = rowb + r;
                if (row < M)
                    C[(size_t)row * N + col] = f2bf(acc[i][j][r] + bv);
            }
        }
    }
}

// ---------------------------------------------------------------------------
// 256^2-tile 8-wave GEMM, BK=32, 3-slot LDS ring, phase-interleaved schedule
// (T2 swizzle + T3/T4 counted vmcnt + T5 setprio).
//   - LDS: 3 slots x (A 256x32 + B 256x32) bf16 = 96 KiB, 1 block/CU.
//   - Swizzle (u16 units): off ^= ((off>>6)&7)<<3  (involution; makes the
//     16-lane row-strided ds_read_b128 a 2-way = free bank pattern).
//   - Staging: global_load_lds width 16; LDS dest linear, per-lane GLOBAL
//     source pre-swizzled with the same involution (m=lane^(lane>>3)).
//   - Ring: iter t reads slot t%3; stages K-tile t+2 into slot (t+2)%3,
//     which all waves finished reading at end of iter t-1 (barrier-proven).
//   - vmcnt(4) once per K-tile (never 0 until tail): waits only for the
//     K-tile staged ~2 iterations ago; next tile's 4 loads stay in flight.
// ---------------------------------------------------------------------------
#define SLOT_U16 16384   // per slot: A 8192 + B 8192 u16

__device__ __forceinline__ void stage_one(
    const u16* __restrict__ G, int gbase, int gmax, int K, int k2,
    const u16* ldsdst, int lane)
{
    int mm = lane ^ (lane >> 3);          // inverse-swizzle the source
    int gr = gbase + (mm >> 2); if (gr > gmax) gr = gmax;
    __builtin_amdgcn_global_load_lds(
        (const __attribute__((address_space(1))) void*)(G + (size_t)gr * K + k2 + (mm & 3) * 8),
        (__attribute__((address_space(3))) void*)ldsdst, 16, 0, 0);
}

__global__ __launch_bounds__(512, 2) void gemm256(
    const u16* __restrict__ A, const u16* __restrict__ W,
    const u16* __restrict__ bias, u16* __restrict__ C,
    int M, int N, int K, int w_row0, int b_off)
{
    __shared__ u16 lds[3 * SLOT_U16];
    const int tid = threadIdx.x;
    const int wid = tid >> 6, lane = tid & 63;

    // supertile swizzle (groups of 8 m-tiles)
    const int MT = (M + 255) >> 8, NT = N >> 8;
    const int tpg = NT * 8;
    const int grp = blockIdx.x / tpg;
    const int rem = blockIdx.x - grp * tpg;
    int gsz = MT - grp * 8; if (gsz > 8) gsz = 8;
    const int mt = grp * 8 + rem % gsz;
    const int nt = rem / gsz;
    const int m0 = mt << 8, n0 = nt << 8;

    const int wmB = (wid >> 2) * 128;   // wave row base (2 row-waves)
    const int wnB = (wid & 3) * 64;     // wave col base (4 col-waves)
    const int r16 = lane & 15, q8 = (lane >> 4) * 8;
    const int w16 = wid * 16;
    const u16* Wb = W + (size_t)w_row0 * K;

    floatx4 acc[8][4];
#pragma unroll
    for (int i = 0; i < 8; ++i)
#pragma unroll
        for (int j = 0; j < 4; ++j)
            acc[i][j] = (floatx4){0.f, 0.f, 0.f, 0.f};

    const int KT = K >> 5;

    // ---- prologue: stage kt0 -> slot0, kt1 -> slot1 ----
#pragma unroll
    for (int t = 0; t < 2; ++t) {
        const int k2 = t << 5;
        const u16* sl = lds + t * SLOT_U16;
        stage_one(A,  m0 + w16,       M - 1, K, k2, sl + w16 * 32, lane);
        stage_one(A,  m0 + 128 + w16, M - 1, K, k2, sl + (128 + w16) * 32, lane);
        stage_one(Wb, n0 + w16,       N - 1, K, k2, sl + 8192 + w16 * 32, lane);
        stage_one(Wb, n0 + 128 + w16, N - 1, K, k2, sl + 8192 + (128 + w16) * 32, lane);
    }
    asm volatile("s_waitcnt vmcnt(4)" ::: "memory");   // kt0 landed; kt1 in flight
    __builtin_amdgcn_s_barrier();

    for (int t = 0; t < KT; ++t) {
        const int slot = t % 3;
        const u16* sAc = lds + slot * SLOT_U16;
        const u16* sBc = sAc + 8192;
        const int t2 = t + 2;
        const u16* sl2 = lds + (t2 % 3) * SLOT_U16;
        const int k2 = t2 << 5;
        const bool dost = t2 < KT;

        short8 bg[4];
        // ================= phase 0 (row-frags 0-3) =================
        short8 af0[4];
#pragma unroll
        for (int i = 0; i < 4; ++i) {
            int ar = wmB + i * 16 + r16;
            int off = ar * 32 + q8;
            af0[i] = *(const short8*)&sAc[off ^ ((((u32)off >> 6) & 7) << 3)];
        }
#pragma unroll
        for (int j = 0; j < 4; ++j) {
            int br = wnB + j * 16 + r16;
            int off = br * 32 + q8;
            bg[j] = *(const short8*)&sBc[off ^ ((((u32)off >> 6) & 7) << 3)];
        }
        if (dost) {
            stage_one(A, m0 + w16,       M - 1, K, k2, sl2 + w16 * 32, lane);
            stage_one(A, m0 + 128 + w16, M - 1, K, k2, sl2 + (128 + w16) * 32, lane);
        }
        __builtin_amdgcn_s_barrier();
        __builtin_amdgcn_s_setprio(1);
#pragma unroll
        for (int i = 0; i < 4; ++i)
#pragma unroll
            for (int j = 0; j < 4; ++j)
                acc[i][j] = __builtin_amdgcn_mfma_f32_16x16x32_bf16(
                    af0[i], bg[j], acc[i][j], 0, 0, 0);
        __builtin_amdgcn_s_setprio(0);
        __builtin_amdgcn_s_barrier();

        // ================= phase 1 (row-frags 4-7) =================
        short8 af1[4];
#pragma unroll
        for (int i = 0; i < 4; ++i) {
            int ar = wmB + 64 + i * 16 + r16;
            int off = ar * 32 + q8;
            af1[i] = *(const short8*)&sAc[off ^ ((((u32)off >> 6) & 7) << 3)];
        }
        if (dost) {
            stage_one(Wb, n0 + w16,       N - 1, K, k2, sl2 + 8192 + w16 * 32, lane);
            stage_one(Wb, n0 + 128 + w16, N - 1, K, k2, sl2 + 8192 + (128 + w16) * 32, lane);
        }
        __builtin_amdgcn_s_barrier();
        __builtin_amdgcn_s_setprio(1);
#pragma unroll
        for (int i = 0; i < 4; ++i)
#pragma unroll
            for (int j = 0; j < 4; ++j)
                acc[4 + i][j] = __builtin_amdgcn_mfma_f32_16x16x32_bf16(
                    af1[i], bg[j], acc[4 + i][j], 0, 0, 0);
        __builtin_amdgcn_s_setprio(0);

        // ---- K-tile boundary: wait for kt t+1 (staged iter t-1), keep
        //      kt t+2's 4 loads in flight. Wave-local wait BEFORE barrier. ----
        if (t < KT - 1) {
            if (t == KT - 2) asm volatile("s_waitcnt vmcnt(0)" ::: "memory");
            else             asm volatile("s_waitcnt vmcnt(4)" ::: "memory");
            __builtin_amdgcn_s_barrier();
        }
    }

    // ---- epilogue ----
#pragma unroll
    for (int j = 0; j < 4; ++j) {
        int col = n0 + wnB + j * 16 + r16;
        float bv = bf2f(bias[b_off + col]);
#pragma unroll
        for (int i = 0; i < 8; ++i) {
            int rowb = m0 + wmB + i * 16 + (lane >> 4) * 4;
#pragma unroll
            for (int r = 0; r < 4; ++r) {
                int row = rowb + r;
                if (row < M)
                    C[(size_t)row * N + col] = f2bf(acc[i][j][r] + bv);
            }
        }
    }
}

// ---------------------------------------------------------------------------
// MFMA flash attention (unchanged — passing).
// ---------------------------------------------------------------------------
__global__ __launch_bounds__(256) void attn_flash(
    const u16* __restrict__ qkv, u16* __restrict__ out, int L, int causal)
{
    __shared__ u16 sK[64 * 64];
    __shared__ u16 sVt[64 * 64];
    __shared__ u16 sP[4 * 16 * 64];
    const int tid = threadIdx.x;
    const int wave = tid >> 6, lane = tid & 63;
    const int h = blockIdx.y, g = blockIdx.z, qt = blockIdx.x;
    const size_t grow0 = (size_t)g * L;
    const int qw0 = qt * 64 + wave * 16;
    const int r16 = lane & 15, q8 = (lane >> 4) * 8;

    short8 qf0, qf1;
    {
        const u16* qp = qkv + (grow0 + qw0 + r16) * (size_t)H3 + h * HD + q8;
        qf0 = *(const short8*)qp;
        qf1 = *(const short8*)(qp + 32);
    }

    floatx4 o_acc[4];
#pragma unroll
    for (int dg = 0; dg < 4; ++dg) o_acc[dg] = (floatx4){0.f, 0.f, 0.f, 0.f};
    float m_r[4], l_r[4];
#pragma unroll
    for (int r = 0; r < 4; ++r) { m_r[r] = -3.0e38f; l_r[r] = 0.f; }

    u16* sPw = sP + wave * 1024;
    const int nch = causal ? (qt + 1) : (L >> 6);

    for (int c = 0; c < nch; ++c) {
        const int k0 = c * 64;
        __syncthreads();
#pragma unroll
        for (int t = 0; t < 2; ++t) {
            int idx = t * 256 + tid;
            int r = idx >> 3, c8 = (idx & 7) * 8;
            const u16* kp = qkv + (grow0 + k0 + r) * (size_t)H3 + EDIM + h * HD + c8;
            *(uint4*)&sK[r * 64 + c8] = *(const uint4*)kp;
            uint4 vw = *(const uint4*)(kp + EDIM);
            u32 vu[4] = {vw.x, vw.y, vw.z, vw.w};
#pragma unroll
            for (int i = 0; i < 4; ++i) {
                sVt[(c8 + 2 * i) * 64 + r]     = (u16)(vu[i] & 0xffffu);
                sVt[(c8 + 2 * i + 1) * 64 + r] = (u16)(vu[i] >> 16);
            }
        }
        __syncthreads();

        float sc[4][4];
#pragma unroll
        for (int kg = 0; kg < 4; ++kg) {
            const u16* kb = &sK[(kg * 16 + r16) * 64];
            short8 kf0 = *(const short8*)(kb + q8);
            short8 kf1 = *(const short8*)(kb + 32 + q8);
            floatx4 a = (floatx4){0.f, 0.f, 0.f, 0.f};
            a = __builtin_amdgcn_mfma_f32_16x16x32_bf16(qf0, kf0, a, 0, 0, 0);
            a = __builtin_amdgcn_mfma_f32_16x16x32_bf16(qf1, kf1, a, 0, 0, 0);
#pragma unroll
            for (int r = 0; r < 4; ++r) sc[kg][r] = a[r] * 0.125f;
        }
        const bool domask = causal && (k0 + 63 > qw0);
        if (domask) {
#pragma unroll
            for (int kg = 0; kg < 4; ++kg)
#pragma unroll
                for (int r = 0; r < 4; ++r) {
                    int key = k0 + kg * 16 + r16;
                    int qg  = qw0 + (lane >> 4) * 4 + r;
                    if (key > qg) sc[kg][r] = -3.0e38f;
                }
        }
        float rmax[4];
#pragma unroll
        for (int r = 0; r < 4; ++r)
            rmax[r] = fmaxf(fmaxf(sc[0][r], sc[1][r]), fmaxf(sc[2][r], sc[3][r]));
#pragma unroll
        for (int m = 1; m <= 8; m <<= 1)
#pragma unroll
            for (int r = 0; r < 4; ++r)
                rmax[r] = fmaxf(rmax[r], __shfl_xor(rmax[r], m));
        float alpha[4], rsum[4];
#pragma unroll
        for (int r = 0; r < 4; ++r) {
            float mn = fmaxf(m_r[r], rmax[r]);
            alpha[r] = __expf(m_r[r] - mn);
            m_r[r] = mn; rsum[r] = 0.f;
        }
#pragma unroll
        for (int kg = 0; kg < 4; ++kg)
#pragma unroll
            for (int r = 0; r < 4; ++r) {
                float p = __expf(sc[kg][r] - m_r[r]);
                rsum[r] += p;
                sPw[((lane >> 4) * 4 + r) * 64 + kg * 16 + r16] = f2bf(p);
            }
#pragma unroll
        for (int m = 1; m <= 8; m <<= 1)
#pragma unroll
            for (int r = 0; r < 4; ++r)
                rsum[r] += __shfl_xor(rsum[r], m);
#pragma unroll
        for (int r = 0; r < 4; ++r) l_r[r] = l_r[r] * alpha[r] + rsum[r];
#pragma unroll
        for (int dg = 0; dg < 4; ++dg)
#pragma unroll
            for (int r = 0; r < 4; ++r) o_acc[dg][r] *= alpha[r];

        __asm__ volatile("" ::: "memory");

#pragma unroll
        for (int kc = 0; kc < 2; ++kc) {
            short8 pf = *(const short8*)&sPw[r16 * 64 + kc * 32 + q8];
#pragma unroll
            for (int dg = 0; dg < 4; ++dg) {
                short8 vf = *(const short8*)&sVt[(dg * 16 + r16) * 64 + kc * 32 + q8];
                o_acc[dg] = __builtin_amdgcn_mfma_f32_16x16x32_bf16(pf, vf, o_acc[dg], 0, 0, 0);
            }
        }
    }

    float inv[4];
#pragma unroll
    for (int r = 0; r < 4; ++r) inv[r] = 1.f / l_r[r];
#pragma unroll
    for (int dg = 0; dg < 4; ++dg)
#pragma unroll
        for (int r = 0; r < 4; ++r) {
            int q = qw0 + (lane >> 4) * 4 + r;
            out[(grow0 + q) * (size_t)EDIM + h * HD + dg * 16 + r16] =
                f2bf(o_acc[dg][r] * inv[r]);
        }
}

// ---------------------------------------------------------------------------
// Single-query cross attention. One wave per (head, group).
// ---------------------------------------------------------------------------
__global__ __launch_bounds__(64) void attn_cross(
    const u16* __restrict__ kv, const u16* __restrict__ qv,
    u16* __restrict__ out, int mode)
{
    const int h = blockIdx.x, gi = blockIdx.y, lane = threadIdx.x;
    int Lk, kvStride, kOff, vOff, qRow;
    size_t kvRow0;
    if (mode == 0) {
        Lk = 256; kvStride = H3; kOff = EDIM; vOff = 2 * EDIM;
        kvRow0 = (size_t)gi * 256;
        int s = gi >> 2, b = gi & 3;
        qRow = b * 16 + s;
    } else {
        Lk = 1040; kvStride = 2 * EDIM; kOff = 0; vOff = EDIM;
        kvRow0 = (size_t)gi * 1040;
        qRow = gi;
    }
    __shared__ float sq[64];
    __shared__ float sp[1040];
    sq[lane] = bf2f(qv[(size_t)qRow * EDIM + h * HD + lane]);
    __syncthreads();

    const int nt = (Lk + 63) >> 6;
    float mloc = -3.0e38f;
    for (int t = 0; t < nt; ++t) {
        int j = t * 64 + lane;
        if (j < Lk) {
            const uint4* kp = (const uint4*)(kv + (kvRow0 + j) * (size_t)kvStride + kOff + h * HD);
            float a0 = 0, a1 = 0;
#pragma unroll
            for (int tt = 0; tt < 8; ++tt) {
                uint4 w = kp[tt];
                u32 u[4] = {w.x, w.y, w.z, w.w};
#pragma unroll
                for (int i = 0; i < 4; ++i) {
                    a0 += sq[tt * 8 + i * 2]     * bf2f((u16)(u[i] & 0xffffu));
                    a1 += sq[tt * 8 + i * 2 + 1] * bf2f((u16)(u[i] >> 16));
                }
            }
            float s_ = (a0 + a1) * 0.125f;
            sp[j] = s_;
            mloc = fmaxf(mloc, s_);
        }
    }
#pragma unroll
    for (int off = 32; off; off >>= 1) mloc = fmaxf(mloc, __shfl_xor(mloc, off));
    float lsum = 0.f;
    for (int t = 0; t < nt; ++t) {
        int j = t * 64 + lane;
        if (j < Lk) { float p = __expf(sp[j] - mloc); sp[j] = p; lsum += p; }
    }
#pragma unroll
    for (int off = 32; off; off >>= 1) lsum += __shfl_xor(lsum, off);
    __syncthreads();

    float o = 0.f;
    for (int j = 0; j < Lk; ++j)
        o += sp[j] * bf2f(kv[(kvRow0 + j) * (size_t)kvStride + vOff + h * HD + lane]);
    out[(size_t)qRow * EDIM + h * HD + lane] = f2bf(o / lsum);
}

// ---------------------------------------------------------------------------
__global__ __launch_bounds__(256) void build_ctx(
    const u16* __restrict__ to, const u16* __restrict__ co, u16* __restrict__ ctx)
{
    int idx = blockIdx.x * 256 + threadIdx.x;
    int row = idx >> 7, c8 = (idx & 127) << 3;
    int b = row / 1040, t = row - b * 1040;
    const u16* src = (t < 1024)
        ? (to + ((size_t)(b * 1024 + t) * EDIM + c8))
        : (co + ((size_t)(b * 16 + (t - 1024)) * EDIM + c8));
    *(uint4*)(ctx + (size_t)row * EDIM + c8) = *(const uint4*)src;
}

// ---------------------------------------------------------------------------
__global__ __launch_bounds__(256) void emit_out(
    const u16* __restrict__ src, void* __restrict__ dst, int n8,
    const int* __restrict__ flag)
{
    int idx = blockIdx.x * 256 + threadIdx.x;
    if (idx >= n8) return;
    const u16* s = src + (size_t)idx * 8;
    if (flag[0]) {
        *(uint4*)((u16*)dst + (size_t)idx * 8) = *(const uint4*)s;
    } else {
        float4 f0, f1;
        f0.x = bf2f(s[0]); f0.y = bf2f(s[1]); f0.z = bf2f(s[2]); f0.w = bf2f(s[3]);
        f1.x = bf2f(s[4]); f1.y = bf2f(s[5]); f1.z = bf2f(s[6]); f1.w = bf2f(s[7]);
        float4* dp = (float4*)dst + (size_t)idx * 2;
        dp[0] = f0; dp[1] = f1;
    }
}

// ---------------------------------------------------------------------------
// Workspace live-range plan unchanged from previous round (peak 168 MB).
// ---------------------------------------------------------------------------
extern "C" void kernel_launch(void* const* d_in, const int* in_sizes, int n_in,
                              void* d_out, int out_size, void* d_ws, size_t ws_size,
                              hipStream_t stream)
{
    const void* text  = d_in[0];
    const void* patch = d_in[1];
    const void* cls   = d_in[2];
    const void* intok = d_in[3];
    const void* t_win  = d_in[4];  const void* t_bin  = d_in[5];
    const void* t_wout = d_in[6];  const void* t_bout = d_in[7];
    const void* p_win  = d_in[8];  const void* p_bin  = d_in[9];
    const void* p_wout = d_in[10]; const void* p_bout = d_in[11];
    const void* i_win  = d_in[12]; const void* i_bin  = d_in[13];
    const void* i_wout = d_in[14]; const void* i_bout = d_in[15];

    u16* ws = (u16*)d_ws;
    int* flag       = (int*)d_ws;
    u16* qkv_text   = ws + 64;
    u16* qkv_patch  = ws + 12582976;
    u16* attn_text  = ws + 62914624;
    u16* attn_patch = ws + 67108928;
    u16* cls_q      = ws + 83886144;
    u16* attn_cls   = ws + 83951680;

    u16* text_bf  = attn_text;
    u16* patch_bf = attn_patch;
    u16* cls_bf   = attn_cls;
    u16* int_bf   = cls_q;
    u16* WT   = qkv_patch;
    u16* WTb  = WT + 3145728;
    u16* WP   = attn_text;
    u16* WPb  = WP + 3145728;
    u16* WO1  = qkv_text;
    u16* WO1b = WO1 + 1048576;
    u16* WO2  = qkv_text + 1049600;
    u16* WO2b = WO2 + 1048576;
    u16* WI   = qkv_text + 4259840;
    u16* WIb  = WI + 3145728;
    u16* WIO  = qkv_text + 7408640;
    u16* WIOb = WIO + 1048576;
    u16* ctx      = qkv_text;
    u16* kv_int   = qkv_patch;
    u16* q_int    = qkv_patch + 8519680;
    u16* attn_int = qkv_patch + 8523776;
    u16* out_ws   = qkv_patch + 8527872;
    u16* to_ws = out_ws;
    u16* po_ws = out_ws + 4194304;
    u16* co_ws = out_ws + 20971520;
    u16* io_ws = out_ws + 21037056;

    dim3 blk(256);
    dim3 blk5(512);
    detect_dtype<<<1, blk, 0, stream>>>((const u16*)text, flag);

    // --- stage 0: convert activations + text QKV weights to bf16 ---
    to_bf16_2<<<dim3(10240), blk, 0, stream>>>(text, text_bf, 524288,
                                               patch, patch_bf, 2097152, flag);
    to_bf16_2<<<dim3(32), blk, 0, stream>>>(cls, cls_bf, 8192, cls, cls_bf, 0, flag);
    to_bf16_2<<<dim3(1538), blk, 0, stream>>>(t_win, WT, 393216, t_bin, WTb, 384, flag);

    // --- text QKV (256-tile pipeline: 16x12 = 192 blocks) ---
    gemm256<<<dim3(192), blk5, 0, stream>>>(text_bf, WT, WTb, qkv_text,
                                            4096, 3072, 1024, 0, 0);
    // --- patch weights (into attn_text region, text_bf now dead) ---
    to_bf16_2<<<dim3(1538), blk, 0, stream>>>(p_win, WP, 393216, p_bin, WPb, 384, flag);
    // --- patch QKV (64x12 = 768 blocks) ---
    gemm256<<<dim3(768), blk5, 0, stream>>>(patch_bf, WP, WPb, qkv_patch,
                                            16384, 3072, 1024, 0, 0);
    gemm_bt_bias<<<dim3(1 * 8), blk, 0, stream>>>(cls_bf, WP, WPb, cls_q,
                                                  64, 1024, 1024, 0, 0);

    // --- attention ---
    attn_flash<<<dim3(16, 16, 4), blk, 0, stream>>>(qkv_text, attn_text, 1024, 1);
    attn_flash<<<dim3(4, 16, 64), blk, 0, stream>>>(qkv_patch, attn_patch, 256, 0);
    attn_cross<<<dim3(16, 64), dim3(64), 0, stream>>>(qkv_patch, cls_q, attn_cls, 0);

    // --- output-proj + INT weights ---
    to_bf16_2<<<dim3(513), blk, 0, stream>>>(t_wout, WO1, 131072, t_bout, WO1b, 128, flag);
    to_bf16_2<<<dim3(513), blk, 0, stream>>>(p_wout, WO2, 131072, p_bout, WO2b, 128, flag);
    to_bf16_2<<<dim3(1538), blk, 0, stream>>>(i_win, WI, 393216, i_bin, WIb, 384, flag);
    to_bf16_2<<<dim3(513), blk, 0, stream>>>(i_wout, WIO, 131072, i_bout, WIOb, 128, flag);

    // --- output projections ---
    gemm_bt_bias<<<dim3(32 * 8), blk, 0, stream>>>(attn_text, WO1, WO1b, to_ws,
                                                   4096, 1024, 1024, 0, 0);
    gemm256<<<dim3(256), blk5, 0, stream>>>(attn_patch, WO2, WO2b, po_ws,
                                            16384, 1024, 1024, 0, 0);
    gemm_bt_bias<<<dim3(1 * 8), blk, 0, stream>>>(attn_cls, WO2, WO2b, co_ws,
                                                  64, 1024, 1024, 0, 0);

    // --- INT path ---
    build_ctx<<<dim3(2080), blk, 0, stream>>>(to_ws, co_ws, ctx);
    gemm256<<<dim3(136), blk5, 0, stream>>>(ctx, WI, WIb, kv_int,
                                            4160, 2048, 1024, 1024, 1024);
    to_bf16_2<<<dim3(2), blk, 0, stream>>>(intok, int_bf, 512, intok, int_bf, 0, flag);
    gemm_bt_bias<<<dim3(1 * 8), blk, 0, stream>>>(int_bf, WI, WIb, q_int,
                                                  4, 1024, 1024, 0, 0);
    attn_cross<<<dim3(16, 4), dim3(64), 0, stream>>>(kv_int, q_int, attn_int, 1);
    gemm_bt_bias<<<dim3(1 * 8), blk, 0, stream>>>(attn_int, WIO, WIOb, io_ws,
                                                  4, 1024, 1024, 0, 0);

    // --- emit ---
    emit_out<<<dim3(10274), blk, 0, stream>>>(out_ws, d_out, 2630144, flag);
}

// Round 3
// 887.362 us; speedup vs baseline: 1.8835x; 1.0782x over previous
//
#include <hip/hip_runtime.h>

typedef unsigned short u16;
typedef unsigned int u32;
typedef __attribute__((ext_vector_type(8))) short short8;
typedef __attribute__((ext_vector_type(4))) float floatx4;

#define EDIM 1024
#define H3   3072
#define HD   64

__device__ __forceinline__ float bf2f(u16 u) {
    union { u32 i; float f; } x; x.i = ((u32)u) << 16; return x.f;
}
__device__ __forceinline__ u16 f2bf(float f) {
    u32 u = __float_as_uint(f);
    u32 r = u + 0x7fffu + ((u >> 16) & 1u);
    return (u16)(r >> 16);
}

// ---------------------------------------------------------------------------
// Detect input dtype (bf16 vs fp32) from bit patterns. flag=1 -> bf16.
// ---------------------------------------------------------------------------
__global__ void detect_dtype(const u16* __restrict__ t, int* __restrict__ flag)
{
    __shared__ int cnt;
    if (threadIdx.x == 0) cnt = 0;
    __syncthreads();
    u16 u = t[threadIdx.x * 2];
    int e = (u >> 7) & 0xFF;
    int ok = (u == 0) || (e >= 108 && e <= 136);
    atomicAdd(&cnt, ok);
    __syncthreads();
    if (threadIdx.x == 0) flag[0] = (cnt >= 128) ? 1 : 0;
}

// ---------------------------------------------------------------------------
// Convert two arrays (fp32->bf16, or plain copy when input already bf16).
// Counts are in units of 8 elements.
// ---------------------------------------------------------------------------
__global__ __launch_bounds__(256) void to_bf16_2(
    const void* __restrict__ sa, u16* __restrict__ da, int na8,
    const void* __restrict__ sb, u16* __restrict__ db, int nb8,
    const int* __restrict__ flag)
{
    int idx = blockIdx.x * 256 + threadIdx.x;
    const void* s; u16* d; long off;
    if (idx < na8) {
        s = sa; d = da; off = (long)idx * 8;
    } else {
        idx -= na8;
        if (idx >= nb8) return;
        s = sb; d = db; off = (long)idx * 8;
    }
    if (flag[0]) {
        *(uint4*)(d + off) = *(const uint4*)((const u16*)s + off);
    } else {
        const float* f = (const float*)s + off;
        float4 f0 = *(const float4*)f;
        float4 f1 = *(const float4*)(f + 4);
        uint4 p;
        p.x = (u32)f2bf(f0.x) | ((u32)f2bf(f0.y) << 16);
        p.y = (u32)f2bf(f0.z) | ((u32)f2bf(f0.w) << 16);
        p.z = (u32)f2bf(f1.x) | ((u32)f2bf(f1.y) << 16);
        p.w = (u32)f2bf(f1.z) | ((u32)f2bf(f1.w) << 16);
        *(uint4*)(d + off) = p;
    }
}

// ---------------------------------------------------------------------------
// 128^2-tile GEMM (m97 structure) — kept for small/narrow shapes.
// ---------------------------------------------------------------------------
__global__ __launch_bounds__(256) void gemm_bt_bias(
    const u16* __restrict__ A, const u16* __restrict__ W,
    const u16* __restrict__ bias, u16* __restrict__ C,
    int M, int N, int K, int w_row0, int b_off)
{
    __shared__ u16 sA[128 * 64];
    __shared__ u16 sB[128 * 64];
    const int tid  = threadIdx.x;
    const int wave = tid >> 6, lane = tid & 63;

    const int MT = (M + 127) >> 7, NT = N >> 7;
    const int tpg = NT * 8;
    const int grp = blockIdx.x / tpg;
    const int rem = blockIdx.x - grp * tpg;
    int gsz = MT - grp * 8; if (gsz > 8) gsz = 8;
    const int mt = grp * 8 + rem % gsz;
    const int nt = rem / gsz;
    const int m0 = mt * 128, n0 = nt * 128;

    const int wm = (wave & 1) * 64, wn = (wave >> 1) * 64;
    const int r16 = lane & 15, q8 = (lane >> 4) * 8;
    const int lrow = lane >> 3, lcol = (lane & 7) * 8;

    floatx4 acc[4][4];
#pragma unroll
    for (int i = 0; i < 4; ++i)
#pragma unroll
        for (int j = 0; j < 4; ++j)
            acc[i][j] = (floatx4){0.f, 0.f, 0.f, 0.f};

    const u16* Wb = W + (size_t)w_row0 * K;
    for (int k0 = 0; k0 < K; k0 += 64) {
#pragma unroll
        for (int t = 0; t < 4; ++t) {
            int rr = wave * 32 + t * 8;
            int ga = m0 + rr + lrow; if (ga > M - 1) ga = M - 1;
            __builtin_amdgcn_global_load_lds(
                (const __attribute__((address_space(1))) void*)(A + (size_t)ga * K + k0 + lcol),
                (__attribute__((address_space(3))) void*)&sA[rr * 64], 16, 0, 0);
            int gb = n0 + rr + lrow; if (gb > N - 1) gb = N - 1;
            __builtin_amdgcn_global_load_lds(
                (const __attribute__((address_space(1))) void*)(Wb + (size_t)gb * K + k0 + lcol),
                (__attribute__((address_space(3))) void*)&sB[rr * 64], 16, 0, 0);
        }
        __syncthreads();
#pragma unroll
        for (int kk = 0; kk < 64; kk += 32) {
            short8 af[4], bg[4];
#pragma unroll
            for (int i = 0; i < 4; ++i)
                af[i] = *(const short8*)&sA[(wm + 16 * i + r16) * 64 + kk + q8];
#pragma unroll
            for (int j = 0; j < 4; ++j)
                bg[j] = *(const short8*)&sB[(wn + 16 * j + r16) * 64 + kk + q8];
#pragma unroll
            for (int i = 0; i < 4; ++i)
#pragma unroll
                for (int j = 0; j < 4; ++j)
                    acc[i][j] = __builtin_amdgcn_mfma_f32_16x16x32_bf16(
                        af[i], bg[j], acc[i][j], 0, 0, 0);
        }
        __syncthreads();
    }

#pragma unroll
    for (int j = 0; j < 4; ++j) {
        int col = n0 + wn + 16 * j + r16;
        float bv = bf2f(bias[b_off + col]);
#pragma unroll
        for (int i = 0; i < 4; ++i) {
            int rowb = m0 + wm + 16 * i + (lane >> 4) * 4;
#pragma unroll
            for (int r = 0; r < 4; ++r) {
                int row = rowb + r;
                if (row < M)
                    C[(size_t)row * N + col] = f2bf(acc[i][j][r] + bv);
            }
        }
    }
}

// ---------------------------------------------------------------------------
// 256^2-tile 8-wave GEMM, BK=32, 4-slot LDS ring (128 KiB), ONE barrier per
// K-tile, counted vmcnt (8 in steady state), prefetch distance 3, setprio
// around MFMA clusters, T2 swizzle (bank-conflict-free, proven round 2).
// Epilogue: acc -> LDS image -> coalesced dwordx4 stores (kills 2x write amp).
// Race proof: iter t reads ONLY slot t&3; stages ONLY slot (t+3)&3 == (t-1)&3,
// whose reads finished before the boundary barrier ending iter t-1. Tile t's
// data is landed because the boundary wait at end of iter t-1 allowed only
// the newest 8 loads (tiles t+1,t+2) to remain outstanding (vmcnt in-order).
// ---------------------------------------------------------------------------
#define SLOT_U16 16384   // per slot: A 8192 + B 8192 u16 (256 rows x 32 cols)

__device__ __forceinline__ void stage_one(
    const u16* __restrict__ G, int gbase, int gmax, int K, int k2,
    const u16* ldsdst, int lane)
{
    int mm = lane ^ (lane >> 3);          // inverse-swizzle the source
    int gr = gbase + (mm >> 2); if (gr > gmax) gr = gmax;
    __builtin_amdgcn_global_load_lds(
        (const __attribute__((address_space(1))) void*)(G + (size_t)gr * K + k2 + (mm & 3) * 8),
        (__attribute__((address_space(3))) void*)ldsdst, 16, 0, 0);
}

__global__ __launch_bounds__(512, 2) void gemm256(
    const u16* __restrict__ A, const u16* __restrict__ W,
    const u16* __restrict__ bias, u16* __restrict__ C,
    int M, int N, int K, int w_row0, int b_off)
{
    __shared__ u16 lds[4 * SLOT_U16];   // 128 KiB ring; reused as C image at end
    const int tid = threadIdx.x;
    const int wid = tid >> 6, lane = tid & 63;

    // supertile swizzle (groups of 8 m-tiles)
    const int MT = (M + 255) >> 8, NT = N >> 8;
    const int tpg = NT * 8;
    const int grp = blockIdx.x / tpg;
    const int rem = blockIdx.x - grp * tpg;
    int gsz = MT - grp * 8; if (gsz > 8) gsz = 8;
    const int mt = grp * 8 + rem % gsz;
    const int nt = rem / gsz;
    const int m0 = mt << 8, n0 = nt << 8;

    const int wmB = (wid >> 2) * 128;   // wave row base (2 row-waves)
    const int wnB = (wid & 3) * 64;     // wave col base (4 col-waves)
    const int r16 = lane & 15, q8 = (lane >> 4) * 8;
    const int w16 = wid * 16;
    const u16* Wb = W + (size_t)w_row0 * K;

    floatx4 acc[8][4];
#pragma unroll
    for (int i = 0; i < 8; ++i)
#pragma unroll
        for (int j = 0; j < 4; ++j)
            acc[i][j] = (floatx4){0.f, 0.f, 0.f, 0.f};

    const int KT = K >> 5;   // requires KT >= 3 (always: K = 1024 or 2048 here)

    // ---- prologue: stage tiles 0,1,2 into slots 0,1,2 ----
#pragma unroll
    for (int pt = 0; pt < 3; ++pt) {
        const int k2 = pt << 5;
        u16* sl = lds + pt * SLOT_U16;
        stage_one(A,  m0 + w16,       M - 1, K, k2, sl + w16 * 32, lane);
        stage_one(A,  m0 + 128 + w16, M - 1, K, k2, sl + (128 + w16) * 32, lane);
        stage_one(Wb, n0 + w16,       N - 1, K, k2, sl + 8192 + w16 * 32, lane);
        stage_one(Wb, n0 + 128 + w16, N - 1, K, k2, sl + 8192 + (128 + w16) * 32, lane);
    }
    asm volatile("s_waitcnt vmcnt(8)" ::: "memory");   // tile0 landed; 1,2 in flight
    __builtin_amdgcn_sched_barrier(0);
    __builtin_amdgcn_s_barrier();

    for (int t = 0; t < KT; ++t) {
        const u16* sAc = lds + (t & 3) * SLOT_U16;
        const u16* sBc = sAc + 8192;

        // ---- early stage issue: tile t+3 -> slot (t+3)&3 ----
        if (t + 3 < KT) {
            const int k2 = (t + 3) << 5;
            u16* sl = lds + ((t + 3) & 3) * SLOT_U16;
            stage_one(A,  m0 + w16,       M - 1, K, k2, sl + w16 * 32, lane);
            stage_one(A,  m0 + 128 + w16, M - 1, K, k2, sl + (128 + w16) * 32, lane);
            stage_one(Wb, n0 + w16,       N - 1, K, k2, sl + 8192 + w16 * 32, lane);
            stage_one(Wb, n0 + 128 + w16, N - 1, K, k2, sl + 8192 + (128 + w16) * 32, lane);
        }

        // ================= phase A (row-frags 0-3) =================
        short8 af0[4], bg[4];
#pragma unroll
        for (int i = 0; i < 4; ++i) {
            int off = (wmB + i * 16 + r16) * 32 + q8;
            af0[i] = *(const short8*)&sAc[off ^ ((((u32)off >> 6) & 7) << 3)];
        }
#pragma unroll
        for (int j = 0; j < 4; ++j) {
            int off = (wnB + j * 16 + r16) * 32 + q8;
            bg[j] = *(const short8*)&sBc[off ^ ((((u32)off >> 6) & 7) << 3)];
        }
        __builtin_amdgcn_s_setprio(1);
#pragma unroll
        for (int i = 0; i < 4; ++i)
#pragma unroll
            for (int j = 0; j < 4; ++j)
                acc[i][j] = __builtin_amdgcn_mfma_f32_16x16x32_bf16(
                    af0[i], bg[j], acc[i][j], 0, 0, 0);
        __builtin_amdgcn_s_setprio(0);

        // ================= phase B (row-frags 4-7) =================
        short8 af1[4];
#pragma unroll
        for (int i = 0; i < 4; ++i) {
            int off = (wmB + 64 + i * 16 + r16) * 32 + q8;
            af1[i] = *(const short8*)&sAc[off ^ ((((u32)off >> 6) & 7) << 3)];
        }
        __builtin_amdgcn_s_setprio(1);
#pragma unroll
        for (int i = 0; i < 4; ++i)
#pragma unroll
            for (int j = 0; j < 4; ++j)
                acc[4 + i][j] = __builtin_amdgcn_mfma_f32_16x16x32_bf16(
                    af1[i], bg[j], acc[4 + i][j], 0, 0, 0);
        __builtin_amdgcn_s_setprio(0);

        // ---- boundary: counted wait (tile t+1 landed; t+2,t+3 in flight) ----
        if (t < KT - 1) {
            if (t + 3 < KT)      asm volatile("s_waitcnt vmcnt(8)" ::: "memory");
            else if (t + 2 < KT) asm volatile("s_waitcnt vmcnt(4)" ::: "memory");
            else                 asm volatile("s_waitcnt vmcnt(0)" ::: "memory");
            __builtin_amdgcn_sched_barrier(0);
            __builtin_amdgcn_s_barrier();
        }
    }

    // ---- epilogue: acc -> LDS image [256][256] u16 -> coalesced stores ----
    __syncthreads();
    u16* img = lds;
#pragma unroll
    for (int j = 0; j < 4; ++j) {
        int col = wnB + j * 16 + r16;
        float bv = bf2f(bias[b_off + n0 + col]);
#pragma unroll
        for (int i = 0; i < 8; ++i) {
            int rowb = wmB + i * 16 + (lane >> 4) * 4;
#pragma unroll
            for (int r = 0; r < 4; ++r)
                img[(rowb + r) * 256 + col] = f2bf(acc[i][j][r] + bv);
        }
    }
    __syncthreads();
#pragma unroll
    for (int p = 0; p < 16; ++p) {
        int r = p * 16 + (tid >> 5);
        int c8 = (tid & 31) * 8;
        int grow = m0 + r;
        if (grow < M)
            *(uint4*)&C[(size_t)grow * N + n0 + c8] = *(const uint4*)&img[r * 256 + c8];
    }
}

// ---------------------------------------------------------------------------
// MFMA flash attention (unchanged — passing).
// ---------------------------------------------------------------------------
__global__ __launch_bounds__(256) void attn_flash(
    const u16* __restrict__ qkv, u16* __restrict__ out, int L, int causal)
{
    __shared__ u16 sK[64 * 64];
    __shared__ u16 sVt[64 * 64];
    __shared__ u16 sP[4 * 16 * 64];
    const int tid = threadIdx.x;
    const int wave = tid >> 6, lane = tid & 63;
    const int h = blockIdx.y, g = blockIdx.z, qt = blockIdx.x;
    const size_t grow0 = (size_t)g * L;
    const int qw0 = qt * 64 + wave * 16;
    const int r16 = lane & 15, q8 = (lane >> 4) * 8;

    short8 qf0, qf1;
    {
        const u16* qp = qkv + (grow0 + qw0 + r16) * (size_t)H3 + h * HD + q8;
        qf0 = *(const short8*)qp;
        qf1 = *(const short8*)(qp + 32);
    }

    floatx4 o_acc[4];
#pragma unroll
    for (int dg = 0; dg < 4; ++dg) o_acc[dg] = (floatx4){0.f, 0.f, 0.f, 0.f};
    float m_r[4], l_r[4];
#pragma unroll
    for (int r = 0; r < 4; ++r) { m_r[r] = -3.0e38f; l_r[r] = 0.f; }

    u16* sPw = sP + wave * 1024;
    const int nch = causal ? (qt + 1) : (L >> 6);

    for (int c = 0; c < nch; ++c) {
        const int k0 = c * 64;
        __syncthreads();
#pragma unroll
        for (int t = 0; t < 2; ++t) {
            int idx = t * 256 + tid;
            int r = idx >> 3, c8 = (idx & 7) * 8;
            const u16* kp = qkv + (grow0 + k0 + r) * (size_t)H3 + EDIM + h * HD + c8;
            *(uint4*)&sK[r * 64 + c8] = *(const uint4*)kp;
            uint4 vw = *(const uint4*)(kp + EDIM);
            u32 vu[4] = {vw.x, vw.y, vw.z, vw.w};
#pragma unroll
            for (int i = 0; i < 4; ++i) {
                sVt[(c8 + 2 * i) * 64 + r]     = (u16)(vu[i] & 0xffffu);
                sVt[(c8 + 2 * i + 1) * 64 + r] = (u16)(vu[i] >> 16);
            }
        }
        __syncthreads();

        float sc[4][4];
#pragma unroll
        for (int kg = 0; kg < 4; ++kg) {
            const u16* kb = &sK[(kg * 16 + r16) * 64];
            short8 kf0 = *(const short8*)(kb + q8);
            short8 kf1 = *(const short8*)(kb + 32 + q8);
            floatx4 a = (floatx4){0.f, 0.f, 0.f, 0.f};
            a = __builtin_amdgcn_mfma_f32_16x16x32_bf16(qf0, kf0, a, 0, 0, 0);
            a = __builtin_amdgcn_mfma_f32_16x16x32_bf16(qf1, kf1, a, 0, 0, 0);
#pragma unroll
            for (int r = 0; r < 4; ++r) sc[kg][r] = a[r] * 0.125f;
        }
        const bool domask = causal && (k0 + 63 > qw0);
        if (domask) {
#pragma unroll
            for (int kg = 0; kg < 4; ++kg)
#pragma unroll
                for (int r = 0; r < 4; ++r) {
                    int key = k0 + kg * 16 + r16;
                    int qg  = qw0 + (lane >> 4) * 4 + r;
                    if (key > qg) sc[kg][r] = -3.0e38f;
                }
        }
        float rmax[4];
#pragma unroll
        for (int r = 0; r < 4; ++r)
            rmax[r] = fmaxf(fmaxf(sc[0][r], sc[1][r]), fmaxf(sc[2][r], sc[3][r]));
#pragma unroll
        for (int m = 1; m <= 8; m <<= 1)
#pragma unroll
            for (int r = 0; r < 4; ++r)
                rmax[r] = fmaxf(rmax[r], __shfl_xor(rmax[r], m));
        float alpha[4], rsum[4];
#pragma unroll
        for (int r = 0; r < 4; ++r) {
            float mn = fmaxf(m_r[r], rmax[r]);
            alpha[r] = __expf(m_r[r] - mn);
            m_r[r] = mn; rsum[r] = 0.f;
        }
#pragma unroll
        for (int kg = 0; kg < 4; ++kg)
#pragma unroll
            for (int r = 0; r < 4; ++r) {
                float p = __expf(sc[kg][r] - m_r[r]);
                rsum[r] += p;
                sPw[((lane >> 4) * 4 + r) * 64 + kg * 16 + r16] = f2bf(p);
            }
#pragma unroll
        for (int m = 1; m <= 8; m <<= 1)
#pragma unroll
            for (int r = 0; r < 4; ++r)
                rsum[r] += __shfl_xor(rsum[r], m);
#pragma unroll
        for (int r = 0; r < 4; ++r) l_r[r] = l_r[r] * alpha[r] + rsum[r];
#pragma unroll
        for (int dg = 0; dg < 4; ++dg)
#pragma unroll
            for (int r = 0; r < 4; ++r) o_acc[dg][r] *= alpha[r];

        __asm__ volatile("" ::: "memory");

#pragma unroll
        for (int kc = 0; kc < 2; ++kc) {
            short8 pf = *(const short8*)&sPw[r16 * 64 + kc * 32 + q8];
#pragma unroll
            for (int dg = 0; dg < 4; ++dg) {
                short8 vf = *(const short8*)&sVt[(dg * 16 + r16) * 64 + kc * 32 + q8];
                o_acc[dg] = __builtin_amdgcn_mfma_f32_16x16x32_bf16(pf, vf, o_acc[dg], 0, 0, 0);
            }
        }
    }

    float inv[4];
#pragma unroll
    for (int r = 0; r < 4; ++r) inv[r] = 1.f / l_r[r];
#pragma unroll
    for (int dg = 0; dg < 4; ++dg)
#pragma unroll
        for (int r = 0; r < 4; ++r) {
            int q = qw0 + (lane >> 4) * 4 + r;
            out[(grow0 + q) * (size_t)EDIM + h * HD + dg * 16 + r16] =
                f2bf(o_acc[dg][r] * inv[r]);
        }
}

// ---------------------------------------------------------------------------
// Single-query cross attention. One wave per (head, group).
// ---------------------------------------------------------------------------
__global__ __launch_bounds__(64) void attn_cross(
    const u16* __restrict__ kv, const u16* __restrict__ qv,
    u16* __restrict__ out, int mode)
{
    const int h = blockIdx.x, gi = blockIdx.y, lane = threadIdx.x;
    int Lk, kvStride, kOff, vOff, qRow;
    size_t kvRow0;
    if (mode == 0) {
        Lk = 256; kvStride = H3; kOff = EDIM; vOff = 2 * EDIM;
        kvRow0 = (size_t)gi * 256;
        int s = gi >> 2, b = gi & 3;
        qRow = b * 16 + s;
    } else {
        Lk = 1040; kvStride = 2 * EDIM; kOff = 0; vOff = EDIM;
        kvRow0 = (size_t)gi * 1040;
        qRow = gi;
    }
    __shared__ float sq[64];
    __shared__ float sp[1040];
    sq[lane] = bf2f(qv[(size_t)qRow * EDIM + h * HD + lane]);
    __syncthreads();

    const int nt = (Lk + 63) >> 6;
    float mloc = -3.0e38f;
    for (int t = 0; t < nt; ++t) {
        int j = t * 64 + lane;
        if (j < Lk) {
            const uint4* kp = (const uint4*)(kv + (kvRow0 + j) * (size_t)kvStride + kOff + h * HD);
            float a0 = 0, a1 = 0;
#pragma unroll
            for (int tt = 0; tt < 8; ++tt) {
                uint4 w = kp[tt];
                u32 u[4] = {w.x, w.y, w.z, w.w};
#pragma unroll
                for (int i = 0; i < 4; ++i) {
                    a0 += sq[tt * 8 + i * 2]     * bf2f((u16)(u[i] & 0xffffu));
                    a1 += sq[tt * 8 + i * 2 + 1] * bf2f((u16)(u[i] >> 16));
                }
            }
            float s_ = (a0 + a1) * 0.125f;
            sp[j] = s_;
            mloc = fmaxf(mloc, s_);
        }
    }
#pragma unroll
    for (int off = 32; off; off >>= 1) mloc = fmaxf(mloc, __shfl_xor(mloc, off));
    float lsum = 0.f;
    for (int t = 0; t < nt; ++t) {
        int j = t * 64 + lane;
        if (j < Lk) { float p = __expf(sp[j] - mloc); sp[j] = p; lsum += p; }
    }
#pragma unroll
    for (int off = 32; off; off >>= 1) lsum += __shfl_xor(lsum, off);
    __syncthreads();

    float o = 0.f;
    for (int j = 0; j < Lk; ++j)
        o += sp[j] * bf2f(kv[(kvRow0 + j) * (size_t)kvStride + vOff + h * HD + lane]);
    out[(size_t)qRow * EDIM + h * HD + lane] = f2bf(o / lsum);
}

// ---------------------------------------------------------------------------
__global__ __launch_bounds__(256) void build_ctx(
    const u16* __restrict__ to, const u16* __restrict__ co, u16* __restrict__ ctx)
{
    int idx = blockIdx.x * 256 + threadIdx.x;
    int row = idx >> 7, c8 = (idx & 127) << 3;
    int b = row / 1040, t = row - b * 1040;
    const u16* src = (t < 1024)
        ? (to + ((size_t)(b * 1024 + t) * EDIM + c8))
        : (co + ((size_t)(b * 16 + (t - 1024)) * EDIM + c8));
    *(uint4*)(ctx + (size_t)row * EDIM + c8) = *(const uint4*)src;
}

// ---------------------------------------------------------------------------
__global__ __launch_bounds__(256) void emit_out(
    const u16* __restrict__ src, void* __restrict__ dst, int n8,
    const int* __restrict__ flag)
{
    int idx = blockIdx.x * 256 + threadIdx.x;
    if (idx >= n8) return;
    const u16* s = src + (size_t)idx * 8;
    if (flag[0]) {
        *(uint4*)((u16*)dst + (size_t)idx * 8) = *(const uint4*)s;
    } else {
        float4 f0, f1;
        f0.x = bf2f(s[0]); f0.y = bf2f(s[1]); f0.z = bf2f(s[2]); f0.w = bf2f(s[3]);
        f1.x = bf2f(s[4]); f1.y = bf2f(s[5]); f1.z = bf2f(s[6]); f1.w = bf2f(s[7]);
        float4* dp = (float4*)dst + (size_t)idx * 2;
        dp[0] = f0; dp[1] = f1;
    }
}

// ---------------------------------------------------------------------------
// Workspace live-range plan unchanged (peak 168 MB).
// ---------------------------------------------------------------------------
extern "C" void kernel_launch(void* const* d_in, const int* in_sizes, int n_in,
                              void* d_out, int out_size, void* d_ws, size_t ws_size,
                              hipStream_t stream)
{
    const void* text  = d_in[0];
    const void* patch = d_in[1];
    const void* cls   = d_in[2];
    const void* intok = d_in[3];
    const void* t_win  = d_in[4];  const void* t_bin  = d_in[5];
    const void* t_wout = d_in[6];  const void* t_bout = d_in[7];
    const void* p_win  = d_in[8];  const void* p_bin  = d_in[9];
    const void* p_wout = d_in[10]; const void* p_bout = d_in[11];
    const void* i_win  = d_in[12]; const void* i_bin  = d_in[13];
    const void* i_wout = d_in[14]; const void* i_bout = d_in[15];

    u16* ws = (u16*)d_ws;
    int* flag       = (int*)d_ws;
    u16* qkv_text   = ws + 64;
    u16* qkv_patch  = ws + 12582976;
    u16* attn_text  = ws + 62914624;
    u16* attn_patch = ws + 67108928;
    u16* cls_q      = ws + 83886144;
    u16* attn_cls   = ws + 83951680;

    u16* text_bf  = attn_text;
    u16* patch_bf = attn_patch;
    u16* cls_bf   = attn_cls;
    u16* int_bf   = cls_q;
    u16* WT   = qkv_patch;
    u16* WTb  = WT + 3145728;
    u16* WP   = attn_text;
    u16* WPb  = WP + 3145728;
    u16* WO1  = qkv_text;
    u16* WO1b = WO1 + 1048576;
    u16* WO2  = qkv_text + 1049600;
    u16* WO2b = WO2 + 1048576;
    u16* WI   = qkv_text + 4259840;
    u16* WIb  = WI + 3145728;
    u16* WIO  = qkv_text + 7408640;
    u16* WIOb = WIO + 1048576;
    u16* ctx      = qkv_text;
    u16* kv_int   = qkv_patch;
    u16* q_int    = qkv_patch + 8519680;
    u16* attn_int = qkv_patch + 8523776;
    u16* out_ws   = qkv_patch + 8527872;
    u16* to_ws = out_ws;
    u16* po_ws = out_ws + 4194304;
    u16* co_ws = out_ws + 20971520;
    u16* io_ws = out_ws + 21037056;

    dim3 blk(256);
    dim3 blk5(512);
    detect_dtype<<<1, blk, 0, stream>>>((const u16*)text, flag);

    // --- stage 0: convert activations + text QKV weights to bf16 ---
    to_bf16_2<<<dim3(10240), blk, 0, stream>>>(text, text_bf, 524288,
                                               patch, patch_bf, 2097152, flag);
    to_bf16_2<<<dim3(32), blk, 0, stream>>>(cls, cls_bf, 8192, cls, cls_bf, 0, flag);
    to_bf16_2<<<dim3(1538), blk, 0, stream>>>(t_win, WT, 393216, t_bin, WTb, 384, flag);

    // --- text QKV (16x12 = 192 blocks) ---
    gemm256<<<dim3(192), blk5, 0, stream>>>(text_bf, WT, WTb, qkv_text,
                                            4096, 3072, 1024, 0, 0);
    // --- patch weights (into attn_text region, text_bf now dead) ---
    to_bf16_2<<<dim3(1538), blk, 0, stream>>>(p_win, WP, 393216, p_bin, WPb, 384, flag);
    // --- patch QKV (64x12 = 768 blocks) ---
    gemm256<<<dim3(768), blk5, 0, stream>>>(patch_bf, WP, WPb, qkv_patch,
                                            16384, 3072, 1024, 0, 0);
    gemm_bt_bias<<<dim3(1 * 8), blk, 0, stream>>>(cls_bf, WP, WPb, cls_q,
                                                  64, 1024, 1024, 0, 0);

    // --- attention ---
    attn_flash<<<dim3(16, 16, 4), blk, 0, stream>>>(qkv_text, attn_text, 1024, 1);
    attn_flash<<<dim3(4, 16, 64), blk, 0, stream>>>(qkv_patch, attn_patch, 256, 0);
    attn_cross<<<dim3(16, 64), dim3(64), 0, stream>>>(qkv_patch, cls_q, attn_cls, 0);

    // --- output-proj + INT weights ---
    to_bf16_2<<<dim3(513), blk, 0, stream>>>(t_wout, WO1, 131072, t_bout, WO1b, 128, flag);
    to_bf16_2<<<dim3(513), blk, 0, stream>>>(p_wout, WO2, 131072, p_bout, WO2b, 128, flag);
    to_bf16_2<<<dim3(1538), blk, 0, stream>>>(i_win, WI, 393216, i_bin, WIb, 384, flag);
    to_bf16_2<<<dim3(513), blk, 0, stream>>>(i_wout, WIO, 131072, i_bout, WIOb, 128, flag);

    // --- output projections ---
    gemm_bt_bias<<<dim3(32 * 8), blk, 0, stream>>>(attn_text, WO1, WO1b, to_ws,
                                                   4096, 1024, 1024, 0, 0);
    gemm256<<<dim3(256), blk5, 0, stream>>>(attn_patch, WO2, WO2b, po_ws,
                                            16384, 1024, 1024, 0, 0);
    gemm_bt_bias<<<dim3(1 * 8), blk, 0, stream>>>(attn_cls, WO2, WO2b, co_ws,
                                                  64, 1024, 1024, 0, 0);

    // --- INT path ---
    build_ctx<<<dim3(2080), blk, 0, stream>>>(to_ws, co_ws, ctx);
    gemm256<<<dim3(136), blk5, 0, stream>>>(ctx, WI, WIb, kv_int,
                                            4160, 2048, 1024, 1024, 1024);
    to_bf16_2<<<dim3(2), blk, 0, stream>>>(intok, int_bf, 512, intok, int_bf, 0, flag);
    gemm_bt_bias<<<dim3(1 * 8), blk, 0, stream>>>(int_bf, WI, WIb, q_int,
                                                  4, 1024, 1024, 0, 0);
    attn_cross<<<dim3(16, 4), dim3(64), 0, stream>>>(kv_int, q_int, attn_int, 1);
    gemm_bt_bias<<<dim3(1 * 8), blk, 0, stream>>>(attn_int, WIO, WIOb, io_ws,
                                                  4, 1024, 1024, 0, 0);

    // --- emit ---
    emit_out<<<dim3(10274), blk, 0, stream>>>(out_ws, d_out, 2630144, flag);
}